// Round 5
// baseline (2958.668 us; speedup 1.0000x reference)
//
#include <hip/hip_runtime.h>
#include <math.h>

// Problem constants
#define B_   16
#define C_   256
#define T_   4096
#define V_   1024
#define K_   4
#define TPB  64      // tokens per block
#define RTP  66      // padded Rt row stride (floats)
#define EPS_CAND 2e-4f

constexpr int Z_ELEMS   = B_ * C_ * T_;        // 16777216
constexpr int IDX_ELEMS = B_ * K_ * T_;        // 262144
constexpr int LOSS_OFF  = Z_ELEMS + IDX_ELEMS; // 17039360

typedef _Float16 h4 __attribute__((ext_vector_type(4)));
typedef float    f4 __attribute__((ext_vector_type(4)));

__global__ void rvq_zero_loss(float* out) { out[LOSS_OFF] = 0.0f; }

// ||c||^2 partials, bit-identical chains to rounds 1-4:
// part0 = fma chain over c = 0..63 then 128..191
// part1 = fma chain over c = 64..127 then 192..255
__global__ void rvq_cvnorm(const float* __restrict__ cb, float2* __restrict__ cvw)
{
    int g = blockIdx.x * 256 + threadIdx.x;   // 0..4095 = st*1024 + v
    const float* row = cb + (size_t)g * C_;
    float p0 = 0.f, p1 = 0.f;
    for (int c = 0;   c < 64;  ++c) p0 = fmaf(row[c], row[c], p0);
    for (int c = 128; c < 192; ++c) p0 = fmaf(row[c], row[c], p0);
    for (int c = 64;  c < 128; ++c) p1 = fmaf(row[c], row[c], p1);
    for (int c = 192; c < 256; ++c) p1 = fmaf(row[c], row[c], p1);
    cvw[g] = make_float2(p0, p1);
}

// Codebook -> f16 B-fragments (scaled by 16 to dodge f16 subnormals).
// elem i of lane l in tile nt, k-step ks = B[k=ks*16+4*(l>>4)+i][n=nt*16+(l&15)]
__global__ void rvq_cbf16(const float* __restrict__ cb, _Float16* __restrict__ cbh)
{
    int gid = blockIdx.x * 256 + threadIdx.x;   // 262144 quads
    int l  = gid & 63;
    int ks = (gid >> 6) & 15;
    int nt = (gid >> 10) & 63;
    int st = gid >> 16;
    int v  = nt * 16 + (l & 15);
    int k  = ks * 16 + 4 * (l >> 4);
    const float* src = cb + ((size_t)(st * V_ + v)) * C_ + k;
    float4 cv = *reinterpret_cast<const float4*>(src);
    h4 o;
    o[0] = (_Float16)(cv.x * 16.0f);
    o[1] = (_Float16)(cv.y * 16.0f);
    o[2] = (_Float16)(cv.z * 16.0f);
    o[3] = (_Float16)(cv.w * 16.0f);
    reinterpret_cast<h4*>(cbh)[gid] = o;
}

__launch_bounds__(512, 4)
__global__ void rvq_main(const float* __restrict__ z,
                         const float* __restrict__ cb,
                         const float2* __restrict__ cvw,
                         const _Float16* __restrict__ cbh,
                         float* __restrict__ out)
{
    __shared__ float Rt[C_][RTP];          // residual, transposed, padded (67.6 KB)
    __shared__ float gmin[8][TPB];         // per-wave token mins; reused for loss
    __shared__ float fmin[TPB];
    __shared__ int   candCnt[TPB];
    __shared__ int   candIdx[TPB][8];
    __shared__ float pbD[TPB][8];
    __shared__ int   pbI[TPB][8];
    __shared__ int   bestIdx[TPB];
    __shared__ float rnpart[TPB][9];
    __shared__ float Rnorm[TPB];

    const int tid = threadIdx.x;           // 0..511
    const int blk = blockIdx.x;
    const int b   = blk >> 6;
    const int t0  = (blk & 63) * TPB;

    const int w   = tid >> 6;              // wave id: n-stripe of 128 vectors
    const int l   = tid & 63;              // lane
    const int ut  = tid & 63;              // update-phase token
    const int ug  = tid >> 6;              // update-phase c-strip (8 x 32)

    // ---- stage residual tile (transposed) ----
    const float* zb = z + (size_t)b * C_ * T_ + t0;
    for (int j = 0; j < 32; ++j) {
        int c = ug * 32 + j;
        Rt[c][ut] = zb[(size_t)c * T_ + ut];
    }
    __syncthreads();
    // ---- Rnorm init (identical chains to rounds 3/4) ----
    {
        float p = 0.f;
        for (int j = 0; j < 32; ++j) { float r = Rt[ug * 32 + j][ut]; p = fmaf(r, r, p); }
        rnpart[ut][ug] = p;
    }
    __syncthreads();
    if (tid < TPB) {
        float s = rnpart[tid][0];
        for (int k = 1; k < 8; ++k) s = __fadd_rn(s, rnpart[tid][k]);
        Rnorm[tid] = s;
    }
    __syncthreads();

    float loss_acc = 0.f;

    // A-fragment addressing (invariant): m = mt*16 + (l&15), k = ks*16 + (l>>4)*4
    const int am   = l & 15;
    const int akof = (l >> 4) * 4;

    for (int st = 0; st < K_; ++st) {
        const float* cbs = cb + (size_t)st * V_ * C_;

        // ---- Phase A: f16 GEMM, acc[mt][nf] = 16 * (r . c) fragments ----
        f4 acc[4][8];
        #pragma unroll
        for (int mt = 0; mt < 4; ++mt)
            #pragma unroll
            for (int nf = 0; nf < 8; ++nf)
                acc[mt][nf] = (f4){0.f, 0.f, 0.f, 0.f};

        {
            const h4* cbh4 = reinterpret_cast<const h4*>(cbh);
            const size_t wbase = (size_t)st * 65536 + (size_t)(w * 8) * 1024 + l;
            #pragma unroll 4
            for (int ks = 0; ks < 16; ++ks) {
                const int kk = ks * 16 + akof;
                h4 af[4];
                #pragma unroll
                for (int mt = 0; mt < 4; ++mt) {
                    const int m = mt * 16 + am;
                    h4 a;
                    a[0] = (_Float16)Rt[kk + 0][m];
                    a[1] = (_Float16)Rt[kk + 1][m];
                    a[2] = (_Float16)Rt[kk + 2][m];
                    a[3] = (_Float16)Rt[kk + 3][m];
                    af[mt] = a;
                }
                #pragma unroll
                for (int nf = 0; nf < 8; ++nf) {
                    h4 bf = cbh4[wbase + (size_t)nf * 1024 + ks * 64];
                    #pragma unroll
                    for (int mt = 0; mt < 4; ++mt)
                        acc[mt][nf] = __builtin_amdgcn_mfma_f32_16x16x16f16(af[mt], bf, acc[mt][nf], 0, 0, 0);
                }
            }
        }

        // ---- convert acc -> approx distances d' = cv2 - 0.125*acc ----
        float cv2v[8];
        #pragma unroll
        for (int nf = 0; nf < 8; ++nf) {
            int v = w * 128 + nf * 16 + (l & 15);
            float2 pv = cvw[st * V_ + v];
            cv2v[nf] = __fadd_rn(pv.x, pv.y);
        }
        #pragma unroll
        for (int mt = 0; mt < 4; ++mt)
            #pragma unroll
            for (int nf = 0; nf < 8; ++nf)
                #pragma unroll
                for (int jj = 0; jj < 4; ++jj)
                    acc[mt][nf][jj] = fmaf(acc[mt][nf][jj], -0.125f, cv2v[nf]);

        // ---- per-token min: lane-local over nf, then across 16 lanes ----
        float tmin[4][4];
        #pragma unroll
        for (int mt = 0; mt < 4; ++mt)
            #pragma unroll
            for (int jj = 0; jj < 4; ++jj) {
                float m0 = acc[mt][0][jj];
                #pragma unroll
                for (int nf = 1; nf < 8; ++nf) m0 = fminf(m0, acc[mt][nf][jj]);
                tmin[mt][jj] = m0;
            }
        #pragma unroll
        for (int mt = 0; mt < 4; ++mt)
            #pragma unroll
            for (int jj = 0; jj < 4; ++jj) {
                float m0 = tmin[mt][jj];
                m0 = fminf(m0, __shfl_xor(m0, 1, 16));
                m0 = fminf(m0, __shfl_xor(m0, 2, 16));
                m0 = fminf(m0, __shfl_xor(m0, 4, 16));
                m0 = fminf(m0, __shfl_xor(m0, 8, 16));
                tmin[mt][jj] = m0;
            }
        if ((l & 15) == 0) {
            #pragma unroll
            for (int mt = 0; mt < 4; ++mt)
                #pragma unroll
                for (int jj = 0; jj < 4; ++jj)
                    gmin[w][mt * 16 + 4 * (l >> 4) + jj] = tmin[mt][jj];
        }
        __syncthreads();
        if (tid < TPB) {
            float mm = gmin[0][tid];
            #pragma unroll
            for (int ww = 1; ww < 8; ++ww) mm = fminf(mm, gmin[ww][tid]);
            fmin[tid] = mm;
            candCnt[tid] = 0;
        }
        __syncthreads();

        // ---- candidate scan & push ----
        {
            float fthr[4][4];
            #pragma unroll
            for (int mt = 0; mt < 4; ++mt)
                #pragma unroll
                for (int jj = 0; jj < 4; ++jj)
                    fthr[mt][jj] = fmin[mt * 16 + 4 * (l >> 4) + jj] + EPS_CAND;
            #pragma unroll
            for (int mt = 0; mt < 4; ++mt)
                #pragma unroll
                for (int nf = 0; nf < 8; ++nf)
                    #pragma unroll
                    for (int jj = 0; jj < 4; ++jj)
                        if (acc[mt][nf][jj] <= fthr[mt][jj]) {
                            int tok = mt * 16 + 4 * (l >> 4) + jj;
                            int s = atomicAdd(&candCnt[tok], 1);
                            if (s < 8) candIdx[tok][s] = w * 128 + nf * 16 + (l & 15);
                        }
        }
        __syncthreads();

        // ---- Phase B: exact fp32-chain distance for candidates ----
        {
            int t = tid & 63, s = tid >> 6;
            int nc = candCnt[t]; if (nc > 8) nc = 8;
            if (s < nc) {
                int gi = candIdx[t][s];
                const float* crow = cbs + (size_t)gi * C_;
                float dot = 0.f;
                for (int c = 0; c < 256; c += 4) {
                    float4 cr = *reinterpret_cast<const float4*>(crow + c);
                    dot = __fadd_rn(dot, __fmul_rn(Rt[c + 0][t], cr.x));
                    dot = __fadd_rn(dot, __fmul_rn(Rt[c + 1][t], cr.y));
                    dot = __fadd_rn(dot, __fmul_rn(Rt[c + 2][t], cr.z));
                    dot = __fadd_rn(dot, __fmul_rn(Rt[c + 3][t], cr.w));
                }
                float2 pv = cvw[st * V_ + gi];
                float cv2 = __fadd_rn(pv.x, pv.y);
                float S = __fadd_rn(Rnorm[t], cv2);
                pbD[t][s] = __fsub_rn(S, 2.0f * dot);
                pbI[t][s] = gi;
            }
        }
        __syncthreads();
        if (tid < TPB) {
            int nc = candCnt[tid]; if (nc > 8) nc = 8;
            float bd = pbD[tid][0];
            int   bi = pbI[tid][0];
            for (int s = 1; s < nc; ++s) {
                float d  = pbD[tid][s];
                int   i2 = pbI[tid][s];
                if (d < bd || (d == bd && i2 < bi)) { bd = d; bi = i2; }
            }
            bestIdx[tid] = bi;
            out[Z_ELEMS + ((size_t)b * K_ + st) * T_ + t0 + tid] = (float)bi;
        }
        __syncthreads();

        // ---- update phase: replicate STE rounding exactly (unchanged) ----
        {
            const float* q = cbs + (size_t)bestIdx[ut] * C_ + ug * 32;
            float rn = 0.f;
            for (int j4 = 0; j4 < 8; ++j4) {
                float4 qv = *reinterpret_cast<const float4*>(q + 4 * j4);
                float qe[4] = { qv.x, qv.y, qv.z, qv.w };
                #pragma unroll
                for (int e = 0; e < 4; ++e) {
                    int c = ug * 32 + 4 * j4 + e;
                    float r   = Rt[c][ut];
                    float qmr = __fsub_rn(qe[e], r);   // sg(q - r)
                    float zq  = __fadd_rn(r, qmr);     // r + sg(q - r)
                    float lt  = __fsub_rn(zq, r);      // sg(zq) - r
                    loss_acc  = fmaf(lt, lt, loss_acc);
                    float rn2 = __fsub_rn(r, zq);      // r - sg(zq)
                    Rt[c][ut] = rn2;
                    rn = fmaf(rn2, rn2, rn);
                }
            }
            rnpart[ut][ug] = rn;
        }
        __syncthreads();
        if (tid < TPB) {
            float s = rnpart[tid][0];
            for (int k = 1; k < 8; ++k) s = __fadd_rn(s, rnpart[tid][k]);
            Rnorm[tid] = s;
        }
        __syncthreads();
    }

    // ---- epilogue: z_q = z - r_final ----
    {
        float* ob = out + (size_t)b * C_ * T_ + t0;
        for (int j = 0; j < 32; ++j) {
            int c = ug * 32 + j;
            ob[(size_t)c * T_ + ut] = __fsub_rn(zb[(size_t)c * T_ + ut], Rt[c][ut]);
        }
    }

    // ---- loss block-reduce -> atomicAdd (reuse gmin as scratch) ----
    __syncthreads();
    float* lred = &gmin[0][0];   // 512 floats
    lred[tid] = loss_acc;
    __syncthreads();
    if (tid < 256) lred[tid] += lred[tid + 256];
    __syncthreads();
    if (tid < 128) lred[tid] += lred[tid + 128];
    __syncthreads();
    if (tid < 64)  lred[tid] += lred[tid + 64];
    __syncthreads();
    if (tid == 0) {
        float s = 0.f;
        for (int i = 0; i < 64; ++i) s += lred[i];
        atomicAdd(out + LOSS_OFF, s * (1.0f / 67108864.0f));  // / (B*T*C) / K
    }
}

extern "C" void kernel_launch(void* const* d_in, const int* in_sizes, int n_in,
                              void* d_out, int out_size, void* d_ws, size_t ws_size,
                              hipStream_t stream)
{
    const float* z  = (const float*)d_in[0];
    const float* cb = (const float*)d_in[1];
    float* out = (float*)d_out;
    float2*    cvw = (float2*)d_ws;                              // 32 KB
    _Float16*  cbh = (_Float16*)((char*)d_ws + 32768);           // 2 MB

    rvq_zero_loss<<<1, 1, 0, stream>>>(out);
    rvq_cvnorm<<<16, 256, 0, stream>>>(cb, cvw);
    rvq_cbf16<<<1024, 256, 0, stream>>>(cb, cbh);
    rvq_main<<<dim3(1024), dim3(512), 0, stream>>>(z, cb, cvw, cbh, out);
}

// Round 6
// 492.917 us; speedup vs baseline: 6.0024x; 6.0024x over previous
//
#include <hip/hip_runtime.h>
#include <math.h>

// Problem constants
#define B_   16
#define C_   256
#define T_   4096
#define V_   1024
#define K_   4
#define TPB  64      // tokens per block
#define RTP  66      // padded Rt row stride (floats) — 2-way-free A-frag reads
#define EPS_CAND 2e-4f

constexpr int Z_ELEMS   = B_ * C_ * T_;        // 16777216
constexpr int IDX_ELEMS = B_ * K_ * T_;        // 262144
constexpr int LOSS_OFF  = Z_ELEMS + IDX_ELEMS; // 17039360

typedef _Float16 h4 __attribute__((ext_vector_type(4)));
typedef float    f4 __attribute__((ext_vector_type(4)));

__global__ void rvq_zero_loss(float* out) { out[LOSS_OFF] = 0.0f; }

// ||c||^2 partials, bit-identical chains to rounds 1-5:
// part0 = fma chain over c = 0..63 then 128..191
// part1 = fma chain over c = 64..127 then 192..255
__global__ void rvq_cvnorm(const float* __restrict__ cb, float2* __restrict__ cvw)
{
    int g = blockIdx.x * 256 + threadIdx.x;   // 0..4095 = st*1024 + v
    const float* row = cb + (size_t)g * C_;
    float p0 = 0.f, p1 = 0.f;
    for (int c = 0;   c < 64;  ++c) p0 = fmaf(row[c], row[c], p0);
    for (int c = 128; c < 192; ++c) p0 = fmaf(row[c], row[c], p0);
    for (int c = 64;  c < 128; ++c) p1 = fmaf(row[c], row[c], p1);
    for (int c = 192; c < 256; ++c) p1 = fmaf(row[c], row[c], p1);
    cvw[g] = make_float2(p0, p1);
}

// Codebook -> f16 B-fragments (scaled by 16 to dodge f16 subnormals).
// elem i of lane l in tile nt, k-step ks = B[k=ks*16+4*(l>>4)+i][n=nt*16+(l&15)]
// flat: cbh4[st*65536 + nt*1024 + ks*64 + l]
__global__ void rvq_cbf16(const float* __restrict__ cb, _Float16* __restrict__ cbh)
{
    int gid = blockIdx.x * 256 + threadIdx.x;   // 262144 quads
    int l  = gid & 63;
    int ks = (gid >> 6) & 15;
    int nt = (gid >> 10) & 63;
    int st = gid >> 16;
    int v  = nt * 16 + (l & 15);
    int k  = ks * 16 + 4 * (l >> 4);
    const float* src = cb + ((size_t)(st * V_ + v)) * C_ + k;
    float4 cv = *reinterpret_cast<const float4*>(src);
    h4 o;
    o[0] = (_Float16)(cv.x * 16.0f);
    o[1] = (_Float16)(cv.y * 16.0f);
    o[2] = (_Float16)(cv.z * 16.0f);
    o[3] = (_Float16)(cv.w * 16.0f);
    reinterpret_cast<h4*>(cbh)[gid] = o;
}

__launch_bounds__(512, 4)
__global__ void rvq_main(const float* __restrict__ z,
                         const float* __restrict__ cb,
                         const float2* __restrict__ cvw,
                         const _Float16* __restrict__ cbh,
                         float* __restrict__ out)
{
    __shared__ float Rt[C_][RTP];          // residual, transposed, padded (67.6 KB)
    __shared__ float gmin[8][TPB];         // per-wave token mins; reused for loss
    __shared__ float fmin[TPB];
    __shared__ int   candCnt[TPB];
    __shared__ int   candIdx[TPB][16];
    __shared__ float pbD[TPB][16];
    __shared__ int   bestIdx[TPB];
    __shared__ float rnpart[TPB][8];
    __shared__ float Rnorm[TPB];

    const int tid = threadIdx.x;           // 0..511
    const int blk = blockIdx.x;
    const int b   = blk >> 6;
    const int t0  = (blk & 63) * TPB;

    const int w   = tid >> 6;              // wave id
    const int l   = tid & 63;              // lane
    const int ut  = tid & 63;              // update-phase token
    const int ug  = tid >> 6;              // update-phase c-strip (8 x 32)

    // ---- stage residual tile (transposed) ----
    const float* zb = z + (size_t)b * C_ * T_ + t0;
    for (int j = 0; j < 32; ++j) {
        int c = ug * 32 + j;
        Rt[c][ut] = zb[(size_t)c * T_ + ut];
    }
    __syncthreads();
    // ---- Rnorm init (identical chains to rounds 3-5) ----
    {
        float p = 0.f;
        for (int j = 0; j < 32; ++j) { float r = Rt[ug * 32 + j][ut]; p = fmaf(r, r, p); }
        rnpart[ut][ug] = p;
    }
    __syncthreads();
    if (tid < TPB) {
        float s = rnpart[tid][0];
        for (int k = 1; k < 8; ++k) s = __fadd_rn(s, rnpart[tid][k]);
        Rnorm[tid] = s;
    }
    __syncthreads();

    float loss_acc = 0.f;

    // A-fragment addressing: m = mt*16 + (l&15), k = ks*16 + (l>>4)*4
    const int am   = l & 15;
    const int akof = (l >> 4) * 4;

    for (int st = 0; st < K_; ++st) {
        const float* cbs = cb + (size_t)st * V_ * C_;

        // ================= two N-passes of 512 vectors each =================
        for (int p = 0; p < 2; ++p) {
            // wave w covers vectors vbase .. vbase+63 (4 n-fragments)
            const int vbase = p * 512 + w * 64;

            f4 acc[4][4];
            #pragma unroll
            for (int mt = 0; mt < 4; ++mt)
                #pragma unroll
                for (int nf = 0; nf < 4; ++nf)
                    acc[mt][nf] = (f4){0.f, 0.f, 0.f, 0.f};

            {
                const h4* cbh4 = reinterpret_cast<const h4*>(cbh);
                const size_t wbase = (size_t)st * 65536 + (size_t)(vbase >> 4) * 1024 + l;
                #pragma unroll 4
                for (int ks = 0; ks < 16; ++ks) {
                    const int kk = ks * 16 + akof;
                    h4 af[4];
                    #pragma unroll
                    for (int mt = 0; mt < 4; ++mt) {
                        const int m = mt * 16 + am;
                        h4 a;
                        a[0] = (_Float16)Rt[kk + 0][m];
                        a[1] = (_Float16)Rt[kk + 1][m];
                        a[2] = (_Float16)Rt[kk + 2][m];
                        a[3] = (_Float16)Rt[kk + 3][m];
                        af[mt] = a;
                    }
                    #pragma unroll
                    for (int nf = 0; nf < 4; ++nf) {
                        h4 bf = cbh4[wbase + (size_t)nf * 1024 + ks * 64];
                        #pragma unroll
                        for (int mt = 0; mt < 4; ++mt)
                            acc[mt][nf] = __builtin_amdgcn_mfma_f32_16x16x16f16(af[mt], bf, acc[mt][nf], 0, 0, 0);
                    }
                }
            }

            // ---- approx distances d' = cv2 - 0.125*acc ----
            float cv2v[4];
            #pragma unroll
            for (int nf = 0; nf < 4; ++nf) {
                int v = vbase + nf * 16 + (l & 15);
                float2 pv = cvw[st * V_ + v];
                cv2v[nf] = __fadd_rn(pv.x, pv.y);
            }
            #pragma unroll
            for (int mt = 0; mt < 4; ++mt)
                #pragma unroll
                for (int nf = 0; nf < 4; ++nf)
                    #pragma unroll
                    for (int jj = 0; jj < 4; ++jj)
                        acc[mt][nf][jj] = fmaf(acc[mt][nf][jj], -0.125f, cv2v[nf]);

            // ---- per-token min (this pass) ----
            float tmin[4][4];
            #pragma unroll
            for (int mt = 0; mt < 4; ++mt)
                #pragma unroll
                for (int jj = 0; jj < 4; ++jj) {
                    float m0 = acc[mt][0][jj];
                    #pragma unroll
                    for (int nf = 1; nf < 4; ++nf) m0 = fminf(m0, acc[mt][nf][jj]);
                    tmin[mt][jj] = m0;
                }
            #pragma unroll
            for (int mt = 0; mt < 4; ++mt)
                #pragma unroll
                for (int jj = 0; jj < 4; ++jj) {
                    float m0 = tmin[mt][jj];
                    m0 = fminf(m0, __shfl_xor(m0, 1, 16));
                    m0 = fminf(m0, __shfl_xor(m0, 2, 16));
                    m0 = fminf(m0, __shfl_xor(m0, 4, 16));
                    m0 = fminf(m0, __shfl_xor(m0, 8, 16));
                    tmin[mt][jj] = m0;
                }
            if ((l & 15) == 0) {
                #pragma unroll
                for (int mt = 0; mt < 4; ++mt)
                    #pragma unroll
                    for (int jj = 0; jj < 4; ++jj)
                        gmin[w][mt * 16 + 4 * (l >> 4) + jj] = tmin[mt][jj];
            }
            __syncthreads();
            if (tid < TPB) {
                float mm = gmin[0][tid];
                #pragma unroll
                for (int ww = 1; ww < 8; ++ww) mm = fminf(mm, gmin[ww][tid]);
                fmin[tid] = mm;
                if (p == 0) candCnt[tid] = 0;
            }
            __syncthreads();

            // ---- candidate scan & push (slots are dense via atomic; cap 16) ----
            {
                float fthr[4][4];
                #pragma unroll
                for (int mt = 0; mt < 4; ++mt)
                    #pragma unroll
                    for (int jj = 0; jj < 4; ++jj)
                        fthr[mt][jj] = fmin[mt * 16 + 4 * (l >> 4) + jj] + EPS_CAND;
                #pragma unroll
                for (int mt = 0; mt < 4; ++mt)
                    #pragma unroll
                    for (int nf = 0; nf < 4; ++nf)
                        #pragma unroll
                        for (int jj = 0; jj < 4; ++jj)
                            if (acc[mt][nf][jj] <= fthr[mt][jj]) {
                                int tok = mt * 16 + 4 * (l >> 4) + jj;
                                int s = atomicAdd(&candCnt[tok], 1);
                                if (s < 16) candIdx[tok][s] = vbase + nf * 16 + (l & 15);
                            }
            }
            __syncthreads();   // scans done before next pass overwrites gmin
        }

        // ---- Phase B: exact fp32-chain distance for candidates ----
        {
            int t = tid & 63, s0 = tid >> 6;
            int nc = candCnt[t]; if (nc > 16) nc = 16;
            for (int s = s0; s < nc; s += 8) {
                int gi = candIdx[t][s];
                const float* crow = cbs + (size_t)gi * C_;
                float dot = 0.f;
                for (int c = 0; c < 256; c += 4) {
                    float4 cr = *reinterpret_cast<const float4*>(crow + c);
                    dot = __fadd_rn(dot, __fmul_rn(Rt[c + 0][t], cr.x));
                    dot = __fadd_rn(dot, __fmul_rn(Rt[c + 1][t], cr.y));
                    dot = __fadd_rn(dot, __fmul_rn(Rt[c + 2][t], cr.z));
                    dot = __fadd_rn(dot, __fmul_rn(Rt[c + 3][t], cr.w));
                }
                float2 pv = cvw[st * V_ + gi];
                float cv2 = __fadd_rn(pv.x, pv.y);
                float S = __fadd_rn(Rnorm[t], cv2);
                pbD[t][s] = __fsub_rn(S, 2.0f * dot);
            }
        }
        __syncthreads();
        if (tid < TPB) {
            int nc = candCnt[tid]; if (nc > 16) nc = 16;
            float bd = pbD[tid][0];
            int   bi = candIdx[tid][0];
            for (int s = 1; s < nc; ++s) {
                float d  = pbD[tid][s];
                int   i2 = candIdx[tid][s];
                if (d < bd || (d == bd && i2 < bi)) { bd = d; bi = i2; }
            }
            bestIdx[tid] = bi;
            out[Z_ELEMS + ((size_t)b * K_ + st) * T_ + t0 + tid] = (float)bi;
        }
        __syncthreads();

        // ---- update phase: replicate STE rounding exactly (unchanged) ----
        {
            const float* q = cbs + (size_t)bestIdx[ut] * C_ + ug * 32;
            float rn = 0.f;
            for (int j4 = 0; j4 < 8; ++j4) {
                float4 qv = *reinterpret_cast<const float4*>(q + 4 * j4);
                float qe[4] = { qv.x, qv.y, qv.z, qv.w };
                #pragma unroll
                for (int e = 0; e < 4; ++e) {
                    int c = ug * 32 + 4 * j4 + e;
                    float r   = Rt[c][ut];
                    float qmr = __fsub_rn(qe[e], r);   // sg(q - r)
                    float zq  = __fadd_rn(r, qmr);     // r + sg(q - r)
                    float lt  = __fsub_rn(zq, r);      // sg(zq) - r
                    loss_acc  = fmaf(lt, lt, loss_acc);
                    float rn2 = __fsub_rn(r, zq);      // r - sg(zq)
                    Rt[c][ut] = rn2;
                    rn = fmaf(rn2, rn2, rn);
                }
            }
            rnpart[ut][ug] = rn;
        }
        __syncthreads();
        if (tid < TPB) {
            float s = rnpart[tid][0];
            for (int k = 1; k < 8; ++k) s = __fadd_rn(s, rnpart[tid][k]);
            Rnorm[tid] = s;
        }
        __syncthreads();
    }

    // ---- epilogue: z_q = z - r_final ----
    {
        float* ob = out + (size_t)b * C_ * T_ + t0;
        for (int j = 0; j < 32; ++j) {
            int c = ug * 32 + j;
            ob[(size_t)c * T_ + ut] = __fsub_rn(zb[(size_t)c * T_ + ut], Rt[c][ut]);
        }
    }

    // ---- loss block-reduce -> atomicAdd (reuse gmin as scratch) ----
    __syncthreads();
    float* lred = &gmin[0][0];   // 512 floats
    lred[tid] = loss_acc;
    __syncthreads();
    if (tid < 256) lred[tid] += lred[tid + 256];
    __syncthreads();
    if (tid < 128) lred[tid] += lred[tid + 128];
    __syncthreads();
    if (tid < 64)  lred[tid] += lred[tid + 64];
    __syncthreads();
    if (tid == 0) {
        float s = 0.f;
        for (int i = 0; i < 64; ++i) s += lred[i];
        atomicAdd(out + LOSS_OFF, s * (1.0f / 67108864.0f));  // / (B*T*C) / K
    }
}

extern "C" void kernel_launch(void* const* d_in, const int* in_sizes, int n_in,
                              void* d_out, int out_size, void* d_ws, size_t ws_size,
                              hipStream_t stream)
{
    const float* z  = (const float*)d_in[0];
    const float* cb = (const float*)d_in[1];
    float* out = (float*)d_out;
    float2*    cvw = (float2*)d_ws;                              // 32 KB
    _Float16*  cbh = (_Float16*)((char*)d_ws + 32768);           // 2 MB

    rvq_zero_loss<<<1, 1, 0, stream>>>(out);
    rvq_cvnorm<<<16, 256, 0, stream>>>(cb, cvw);
    rvq_cbf16<<<1024, 256, 0, stream>>>(cb, cbh);
    rvq_main<<<dim3(1024), dim3(512), 0, stream>>>(z, cb, cvw, cbh, out);
}

// Round 7
// 489.176 us; speedup vs baseline: 6.0483x; 1.0076x over previous
//
#include <hip/hip_runtime.h>
#include <math.h>

// Problem constants
#define B_   16
#define C_   256
#define T_   4096
#define V_   1024
#define K_   4
#define TPB  64      // tokens per block
#define RTP  66      // padded Rt row stride (floats) — 2-way-free A-frag reads
#define EPS_CAND 2e-4f

constexpr int Z_ELEMS   = B_ * C_ * T_;        // 16777216
constexpr int IDX_ELEMS = B_ * K_ * T_;        // 262144
constexpr int LOSS_OFF  = Z_ELEMS + IDX_ELEMS; // 17039360

typedef _Float16 h8 __attribute__((ext_vector_type(8)));
typedef float    f4 __attribute__((ext_vector_type(4)));

__global__ void rvq_zero_loss(float* out) { out[LOSS_OFF] = 0.0f; }

// ||c||^2 partials, bit-identical chains to rounds 1-6:
// part0 = fma chain over c = 0..63 then 128..191
// part1 = fma chain over c = 64..127 then 192..255
__global__ void rvq_cvnorm(const float* __restrict__ cb, float2* __restrict__ cvw)
{
    int g = blockIdx.x * 256 + threadIdx.x;   // 0..4095 = st*1024 + v
    const float* row = cb + (size_t)g * C_;
    float p0 = 0.f, p1 = 0.f;
    for (int c = 0;   c < 64;  ++c) p0 = fmaf(row[c], row[c], p0);
    for (int c = 128; c < 192; ++c) p0 = fmaf(row[c], row[c], p0);
    for (int c = 64;  c < 128; ++c) p1 = fmaf(row[c], row[c], p1);
    for (int c = 192; c < 256; ++c) p1 = fmaf(row[c], row[c], p1);
    cvw[g] = make_float2(p0, p1);
}

// Codebook -> f16 B-fragments for mfma_f32_16x16x32_f16 (scaled by 16).
// lane l, elem i of tile nt, k-step ks = B[k=ks*32+(l>>4)*8+i][n=nt*16+(l&15)]
// flat h8 index: ((st*64 + nt)*8 + ks)*64 + l
__global__ void rvq_cbf16(const float* __restrict__ cb, _Float16* __restrict__ cbh)
{
    int gid = blockIdx.x * 256 + threadIdx.x;   // 131072 h8 quads
    int l  = gid & 63;
    int ks = (gid >> 6) & 7;
    int nt = (gid >> 9) & 63;
    int st = gid >> 15;
    int v  = nt * 16 + (l & 15);
    int k  = ks * 32 + (l >> 4) * 8;
    const float* src = cb + ((size_t)(st * V_ + v)) * C_ + k;
    float4 c0 = *reinterpret_cast<const float4*>(src);
    float4 c1 = *reinterpret_cast<const float4*>(src + 4);
    h8 o;
    o[0] = (_Float16)(c0.x * 16.0f);
    o[1] = (_Float16)(c0.y * 16.0f);
    o[2] = (_Float16)(c0.z * 16.0f);
    o[3] = (_Float16)(c0.w * 16.0f);
    o[4] = (_Float16)(c1.x * 16.0f);
    o[5] = (_Float16)(c1.y * 16.0f);
    o[6] = (_Float16)(c1.z * 16.0f);
    o[7] = (_Float16)(c1.w * 16.0f);
    reinterpret_cast<h8*>(cbh)[gid] = o;
}

__launch_bounds__(512, 4)
__global__ void rvq_main(const float* __restrict__ z,
                         const float* __restrict__ cb,
                         const float2* __restrict__ cvw,
                         const _Float16* __restrict__ cbh,
                         float* __restrict__ out)
{
    __shared__ float Rt[C_][RTP];          // residual, transposed, padded (67.6 KB)
    __shared__ float gmin[8][TPB];         // per-wave token mins; reused for loss
    __shared__ int   candCnt[TPB];
    __shared__ int   candIdx[TPB][16];
    __shared__ float pbD[TPB][16];
    __shared__ int   bestIdx[TPB];
    __shared__ float rnpart[TPB][8];
    __shared__ float Rnorm[TPB];

    const int tid = threadIdx.x;           // 0..511
    const int blk = blockIdx.x;
    const int b   = blk >> 6;
    const int t0  = (blk & 63) * TPB;

    const int w   = tid >> 6;              // wave id
    const int l   = tid & 63;              // lane
    const int wv  = w >> 1;                // vector stripe (128 vectors)
    const int th  = (w & 1) * 32;          // token half base
    const int ut  = tid & 63;              // update-phase token
    const int ug  = tid >> 6;              // update-phase c-strip (8 x 32)

    // ---- stage residual tile (transposed) ----
    const float* zb = z + (size_t)b * C_ * T_ + t0;
    for (int j = 0; j < 32; ++j) {
        int c = ug * 32 + j;
        Rt[c][ut] = zb[(size_t)c * T_ + ut];
    }
    __syncthreads();
    // ---- Rnorm init (identical chains to rounds 3-6) ----
    {
        float p = 0.f;
        for (int j = 0; j < 32; ++j) { float r = Rt[ug * 32 + j][ut]; p = fmaf(r, r, p); }
        rnpart[ut][ug] = p;
    }
    __syncthreads();
    if (tid < TPB) {
        float s = rnpart[tid][0];
        for (int k = 1; k < 8; ++k) s = __fadd_rn(s, rnpart[tid][k]);
        Rnorm[tid] = s;
    }
    __syncthreads();

    float loss_acc = 0.f;

    // fragment lane decomposition
    const int am   = l & 15;               // m within 16-tile / n within 16-tile
    const int akof = (l >> 4) * 8;         // k sub-block offset (K=32 frag)

    for (int st = 0; st < K_; ++st) {
        const float* cbs = cb + (size_t)st * V_ * C_;

        // ============ two N-passes; wave covers 32 tok x 128 vec ============
        for (int p = 0; p < 2; ++p) {
            const int vbase = p * 512 + wv * 128;

            f4 acc[2][8];
            #pragma unroll
            for (int mt = 0; mt < 2; ++mt)
                #pragma unroll
                for (int nf = 0; nf < 8; ++nf)
                    acc[mt][nf] = (f4){0.f, 0.f, 0.f, 0.f};

            {
                const h8* cbh8 = reinterpret_cast<const h8*>(cbh);
                const size_t wbase = ((size_t)(st * 64 + (vbase >> 4)) * 8) * 64 + l;
                #pragma unroll 2
                for (int ks = 0; ks < 8; ++ks) {
                    const int k0 = ks * 32 + akof;
                    h8 af[2];
                    #pragma unroll
                    for (int mt = 0; mt < 2; ++mt) {
                        const int m = th + mt * 16 + am;
                        h8 a;
                        #pragma unroll
                        for (int i = 0; i < 8; ++i)
                            a[i] = (_Float16)Rt[k0 + i][m];
                        af[mt] = a;
                    }
                    #pragma unroll
                    for (int nf = 0; nf < 8; ++nf) {
                        h8 bf = cbh8[wbase + (size_t)(nf * 8 + ks) * 64];
                        #pragma unroll
                        for (int mt = 0; mt < 2; ++mt)
                            acc[mt][nf] = __builtin_amdgcn_mfma_f32_16x16x32_f16(af[mt], bf, acc[mt][nf], 0, 0, 0);
                    }
                }
            }

            // ---- approx distances d' = cv2 - 0.125*acc ----
            float cv2v[8];
            #pragma unroll
            for (int nf = 0; nf < 8; ++nf) {
                int v = vbase + nf * 16 + am;
                float2 pv = cvw[st * V_ + v];
                cv2v[nf] = __fadd_rn(pv.x, pv.y);
            }
            #pragma unroll
            for (int mt = 0; mt < 2; ++mt)
                #pragma unroll
                for (int nf = 0; nf < 8; ++nf)
                    #pragma unroll
                    for (int jj = 0; jj < 4; ++jj)
                        acc[mt][nf][jj] = fmaf(acc[mt][nf][jj], -0.125f, cv2v[nf]);

            // ---- per-wave per-token min ----
            float tmin[2][4];
            #pragma unroll
            for (int mt = 0; mt < 2; ++mt)
                #pragma unroll
                for (int jj = 0; jj < 4; ++jj) {
                    float m0 = acc[mt][0][jj];
                    #pragma unroll
                    for (int nf = 1; nf < 8; ++nf) m0 = fminf(m0, acc[mt][nf][jj]);
                    m0 = fminf(m0, __shfl_xor(m0, 1, 16));
                    m0 = fminf(m0, __shfl_xor(m0, 2, 16));
                    m0 = fminf(m0, __shfl_xor(m0, 4, 16));
                    m0 = fminf(m0, __shfl_xor(m0, 8, 16));
                    tmin[mt][jj] = m0;
                }
            if (am == 0) {
                #pragma unroll
                for (int mt = 0; mt < 2; ++mt)
                    #pragma unroll
                    for (int jj = 0; jj < 4; ++jj)
                        gmin[w][th + mt * 16 + 4 * (l >> 4) + jj] = tmin[mt][jj];
            }
            if (p == 0 && tid < TPB) candCnt[tid] = 0;
            __syncthreads();

            // ---- candidate scan & push (pass-local min window; superset) ----
            {
                const int wb = w & 1;   // waves {wb, wb+2, wb+4, wb+6} cover these tokens
                #pragma unroll
                for (int mt = 0; mt < 2; ++mt)
                    #pragma unroll
                    for (int jj = 0; jj < 4; ++jj) {
                        int t = th + mt * 16 + 4 * (l >> 4) + jj;
                        float fm = fminf(fminf(gmin[wb][t], gmin[wb + 2][t]),
                                         fminf(gmin[wb + 4][t], gmin[wb + 6][t]));
                        float fthr = fm + EPS_CAND;
                        #pragma unroll
                        for (int nf = 0; nf < 8; ++nf)
                            if (acc[mt][nf][jj] <= fthr) {
                                int s = atomicAdd(&candCnt[t], 1);
                                if (s < 16) candIdx[t][s] = vbase + nf * 16 + am;
                            }
                    }
            }
            __syncthreads();   // scans done before next pass overwrites gmin
        }

        // ---- Phase B: exact fp32-chain distance for candidates ----
        {
            int t = tid & 63, s0 = tid >> 6;
            int nc = candCnt[t]; if (nc > 16) nc = 16;
            for (int s = s0; s < nc; s += 8) {
                int gi = candIdx[t][s];
                const float* crow = cbs + (size_t)gi * C_;
                float dot = 0.f;
                for (int c = 0; c < 256; c += 4) {
                    float4 cr = *reinterpret_cast<const float4*>(crow + c);
                    dot = __fadd_rn(dot, __fmul_rn(Rt[c + 0][t], cr.x));
                    dot = __fadd_rn(dot, __fmul_rn(Rt[c + 1][t], cr.y));
                    dot = __fadd_rn(dot, __fmul_rn(Rt[c + 2][t], cr.z));
                    dot = __fadd_rn(dot, __fmul_rn(Rt[c + 3][t], cr.w));
                }
                float2 pv = cvw[st * V_ + gi];
                float cv2 = __fadd_rn(pv.x, pv.y);
                float S = __fadd_rn(Rnorm[t], cv2);
                pbD[t][s] = __fsub_rn(S, 2.0f * dot);
            }
        }
        __syncthreads();
        if (tid < TPB) {
            int nc = candCnt[tid]; if (nc > 16) nc = 16;
            float bd = pbD[tid][0];
            int   bi = candIdx[tid][0];
            for (int s = 1; s < nc; ++s) {
                float d  = pbD[tid][s];
                int   i2 = candIdx[tid][s];
                if (d < bd || (d == bd && i2 < bi)) { bd = d; bi = i2; }
            }
            bestIdx[tid] = bi;
            out[Z_ELEMS + ((size_t)b * K_ + st) * T_ + t0 + tid] = (float)bi;
        }
        __syncthreads();

        // ---- update phase: replicate STE rounding exactly (unchanged) ----
        {
            const float* q = cbs + (size_t)bestIdx[ut] * C_ + ug * 32;
            float rn = 0.f;
            for (int j4 = 0; j4 < 8; ++j4) {
                float4 qv = *reinterpret_cast<const float4*>(q + 4 * j4);
                float qe[4] = { qv.x, qv.y, qv.z, qv.w };
                #pragma unroll
                for (int e = 0; e < 4; ++e) {
                    int c = ug * 32 + 4 * j4 + e;
                    float r   = Rt[c][ut];
                    float qmr = __fsub_rn(qe[e], r);   // sg(q - r)
                    float zq  = __fadd_rn(r, qmr);     // r + sg(q - r)
                    float lt  = __fsub_rn(zq, r);      // sg(zq) - r
                    loss_acc  = fmaf(lt, lt, loss_acc);
                    float rn2 = __fsub_rn(r, zq);      // r - sg(zq)
                    Rt[c][ut] = rn2;
                    rn = fmaf(rn2, rn2, rn);
                }
            }
            rnpart[ut][ug] = rn;
        }
        __syncthreads();
        if (tid < TPB) {
            float s = rnpart[tid][0];
            for (int k = 1; k < 8; ++k) s = __fadd_rn(s, rnpart[tid][k]);
            Rnorm[tid] = s;
        }
        __syncthreads();
    }

    // ---- epilogue: z_q = z - r_final ----
    {
        float* ob = out + (size_t)b * C_ * T_ + t0;
        for (int j = 0; j < 32; ++j) {
            int c = ug * 32 + j;
            ob[(size_t)c * T_ + ut] = __fsub_rn(zb[(size_t)c * T_ + ut], Rt[c][ut]);
        }
    }

    // ---- loss block-reduce -> atomicAdd (reuse gmin as scratch) ----
    __syncthreads();
    float* lred = &gmin[0][0];   // 512 floats
    lred[tid] = loss_acc;
    __syncthreads();
    if (tid < 256) lred[tid] += lred[tid + 256];
    __syncthreads();
    if (tid < 128) lred[tid] += lred[tid + 128];
    __syncthreads();
    if (tid < 64)  lred[tid] += lred[tid + 64];
    __syncthreads();
    if (tid == 0) {
        float s = 0.f;
        for (int i = 0; i < 64; ++i) s += lred[i];
        atomicAdd(out + LOSS_OFF, s * (1.0f / 67108864.0f));  // / (B*T*C) / K
    }
}

extern "C" void kernel_launch(void* const* d_in, const int* in_sizes, int n_in,
                              void* d_out, int out_size, void* d_ws, size_t ws_size,
                              hipStream_t stream)
{
    const float* z  = (const float*)d_in[0];
    const float* cb = (const float*)d_in[1];
    float* out = (float*)d_out;
    float2*    cvw = (float2*)d_ws;                              // 32 KB
    _Float16*  cbh = (_Float16*)((char*)d_ws + 32768);           // 2 MB

    rvq_zero_loss<<<1, 1, 0, stream>>>(out);
    rvq_cvnorm<<<16, 256, 0, stream>>>(cb, cvw);
    rvq_cbf16<<<512, 256, 0, stream>>>(cb, cbh);
    rvq_main<<<dim3(1024), dim3(512), 0, stream>>>(z, cb, cvw, cbh, out);
}